// Round 6
// baseline (281409.863 us; speedup 1.0000x reference)
//
#include <hip/hip_runtime.h>
#include <math.h>

// Invariant-EKF sequential scan, SINGLE WAVE (64 lanes, 1 CU, 1 SIMD).
// Rationale (round-5 counters): 7-wave version was latency-bound — CU-level
// VALUBusy ~29%, ~70% stall from 5x per-step {LDS round-trip + barrier gated
// by slowest of 7 asymmetric waves} + 4x replicated state math. With a
// 64-thread workgroup, __syncthreads() lowers to a waitcnt only (no s_barrier,
// no inter-wave skew). Each lane owns 7 of the 441 P elements in registers.
// All arithmetic keeps the exact operand order of the previous PASSING kernel.

#define GRAV 9.80665f
#define LDP 22   // 21x21 matrix row pitch (floats)
#define SP  24   // H row pitch
#define Q0c 0.001f
#define Q1c 0.01f

__device__ __forceinline__ float sel3f(int r, float a, float b, float c) {
    return (r == 0) ? a : ((r == 1) ? b : c);
}

__device__ __forceinline__ void m3mul_dev(const float* A, const float* B, float* C) {
#pragma unroll
    for (int i = 0; i < 3; ++i) {
#pragma unroll
        for (int j = 0; j < 3; ++j) {
            C[i*3+j] = A[i*3+0]*B[j] + A[i*3+1]*B[3+j] + A[i*3+2]*B[6+j];
        }
    }
}

__device__ __forceinline__ void so3exp_dev(float p0, float p1, float p2, float* R) {
    float sq = p0*p0 + p1*p1 + p2*p2;
    if (sq < 1e-16f) {
        R[0]=1.f;  R[1]=-p2;  R[2]=p1;
        R[3]=p2;   R[4]=1.f;  R[5]=-p0;
        R[6]=-p1;  R[7]=p0;   R[8]=1.f;
    } else {
        float ang = sqrtf(sq);
        float ax=p0/ang, ay=p1/ang, az=p2/ang;
        float s=sinf(ang), c=cosf(ang), o=1.f-c;
        R[0]=c+o*ax*ax;    R[1]=o*ax*ay-s*az; R[2]=o*ax*az+s*ay;
        R[3]=o*ay*ax+s*az; R[4]=c+o*ay*ay;    R[5]=o*ay*az-s*ax;
        R[6]=o*az*ax-s*ay; R[7]=o*az*ay+s*ax; R[8]=c+o*az*az;
    }
}

// lanes 0..32 write the 33 trajectory scalars for row NIDX
#define STORE_TRAJ(NIDX)                                                        \
    do {                                                                        \
        if (l < 33) {                                                           \
            float val = Rot[0];                                                 \
            if (l==1) val=Rot[1];  if (l==2) val=Rot[2];                        \
            if (l==3) val=Rot[3];  if (l==4) val=Rot[4];                        \
            if (l==5) val=Rot[5];  if (l==6) val=Rot[6];                        \
            if (l==7) val=Rot[7];  if (l==8) val=Rot[8];                        \
            if (l==9)  val=vv[0];  if (l==10) val=vv[1];  if (l==11) val=vv[2]; \
            if (l==12) val=pp[0];  if (l==13) val=pp[1];  if (l==14) val=pp[2]; \
            if (l==15) val=bw[0];  if (l==16) val=bw[1];  if (l==17) val=bw[2]; \
            if (l==18) val=ba[0];  if (l==19) val=ba[1];  if (l==20) val=ba[2]; \
            if (l==21) val=Rci[0]; if (l==22) val=Rci[1]; if (l==23) val=Rci[2];\
            if (l==24) val=Rci[3]; if (l==25) val=Rci[4]; if (l==26) val=Rci[5];\
            if (l==27) val=Rci[6]; if (l==28) val=Rci[7]; if (l==29) val=Rci[8];\
            if (l==30) val=tci[0]; if (l==31) val=tci[1]; if (l==32) val=tci[2];\
            out[ob + os_ * (NIDX) + orr] = val;                                 \
        }                                                                       \
    } while (0)

__global__ __launch_bounds__(64)
void iekf_scan_kernel(const float* __restrict__ t,
                      const float* __restrict__ u,
                      const float* __restrict__ mc,
                      const float* __restrict__ v_mes,
                      const float* __restrict__ ang0,
                      float* __restrict__ out,
                      const int N)
{
    __shared__ __align__(16) float sA [21*LDP];
    __shared__ __align__(16) float sT1[21*LDP];
    __shared__ __align__(16) float sPn[21*LDP];
    __shared__ __align__(16) float sRows[9*4];   // GQGT row table: rows 0-2=Rot, 3-5=M1, 6-8=M2
    __shared__ __align__(16) float sPhiB[9*8];   // per-row Phi coeffs: [i][0..2]=cbw, [3..5]=cba
    __shared__ __align__(16) float sH  [2*SP];
    __shared__ __align__(16) float sHpack[21*4]; // (hp0,hp1,ht0,ht1) per column
    __shared__ __align__(16) float sKpack[21*4]; // (k0,k1,ks0,ks1) per row
    __shared__ __align__(16) float sdx [SP];
    __shared__ __align__(16) float sS  [4];
    __shared__ float sr[2];

    const int l = (int)threadIdx.x;  // 0..63, single wave

    // ---- per-lane element mapping: element e = 64*q + l, (i,j) = (e/21, e%21)
    int ei[7], ej[7], eoff[7];
    bool ev[7], awr[7], twr[7], gq[7];
#pragma unroll
    for (int q = 0; q < 7; ++q) {
        const int e = 64*q + l;
        const bool v = (e < 441);
        int ii = v ? (e / 21) : 0;
        int jj = v ? (e - ii*21) : 0;
        ev[q] = v; ei[q] = ii; ej[q] = jj; eoff[q] = ii*LDP + jj;
        awr[q] = v && ((ii < 6 && ii != 2) || (ii >= 9 && ii < 15));  // A rows read by T1
        twr[q] = v && ((jj < 6 && jj != 2) || (jj >= 9 && jj < 15));  // T1 cols read by Pn
        gq[q]  = v && (ii < 9) && (jj < 9);
    }

    // ---- small state (replicated in all 64 lanes) ----
    float Rot[9], vv[3], pp[3], bw[3], ba[3], Rci[9], tci[3];
    {
        const float roll = ang0[0], pitch = ang0[1], yaw = ang0[2];
        const float cr = cosf(roll),  srl = sinf(roll);
        const float cp = cosf(pitch), spt = sinf(pitch);
        const float cy = cosf(yaw),   syw = sinf(yaw);
        float rx[9] = {1.f,0.f,0.f, 0.f,cr,-srl, 0.f,srl,cr};
        float ry[9] = {cp,0.f,spt, 0.f,1.f,0.f, -spt,0.f,cp};
        float rz[9] = {cy,-syw,0.f, syw,cy,0.f, 0.f,0.f,1.f};
        float tm[9]; m3mul_dev(rz, ry, tm);
        m3mul_dev(tm, rx, Rot);
        vv[0]=v_mes[0]; vv[1]=v_mes[1]; vv[2]=v_mes[2];
#pragma unroll
        for (int c=0;c<3;c++){ pp[c]=0.f; bw[c]=0.f; ba[c]=0.f; tci[c]=0.f; }
        Rci[0]=1.f;Rci[1]=0.f;Rci[2]=0.f;Rci[3]=0.f;Rci[4]=1.f;Rci[5]=0.f;
        Rci[6]=0.f;Rci[7]=0.f;Rci[8]=1.f;
    }

    // ---- P diag init per owned element ----
    float Preg[7];
#pragma unroll
    for (int q = 0; q < 7; ++q) {
        float pd = 0.f;
        if (ev[q] && ei[q] == ej[q]) {
            const int ii = ei[q];
            if (ii==0 || ii==1)        pd = 0.001f;
            else if (ii==3 || ii==4)   pd = 0.1f;
            else if (ii>=9  && ii<12)  pd = 0.006f;
            else if (ii>=12 && ii<15)  pd = 0.004f;
            else if (ii>=15 && ii<18)  pd = 1e-6f;
            else if (ii>=18)           pd = 0.005f;
        }
        Preg[q] = pd;
    }

    // ---- output address constants (lanes 0..32) ----
    int ob=0, os_=0, orr=0;
    if (l<33) {
        if (l<9)       { ob = 0;    os_ = 9; orr = l;    }
        else if (l<12) { ob = 9*N;  os_ = 3; orr = l-9;  }
        else if (l<15) { ob = 12*N; os_ = 3; orr = l-12; }
        else if (l<18) { ob = 15*N; os_ = 3; orr = l-15; }
        else if (l<21) { ob = 18*N; os_ = 3; orr = l-18; }
        else if (l<30) { ob = 21*N; os_ = 9; orr = l-21; }
        else           { ob = 30*N; os_ = 3; orr = l-30; }
    }

    STORE_TRAJ(0);

    float t_cur = t[0];

    // ---- software-pipelined inputs (uniform -> scalar loads) ----
    float tn_c = t[1];
    float uc0,uc1,uc2,uc3,uc4,uc5;
    { const float* un = u + 6; uc0=un[0]; uc1=un[1]; uc2=un[2]; uc3=un[3]; uc4=un[4]; uc5=un[5]; }
    float mcc0 = mc[2], mcc1 = mc[3];

    for (int n = 0; n < N-1; ++n) {
        // ---- prefetch next iteration's inputs ----
        const int np2 = (n+2 < N) ? (n+2) : (N-1);
        const float tn_n = t[np2];
        float un0,un1,un2,un3,un4,un5;
        { const float* un = u + (size_t)np2*6; un0=un[0]; un1=un[1]; un2=un[2]; un3=un[3]; un4=un[4]; un5=un[5]; }
        const float mcn0 = mc[2*np2], mcn1 = mc[2*np2+1];

        const float dt  = tn_c - t_cur;
        const float dt2 = dt*dt;
        const float u0=uc0,u1=uc1,u2=uc2,u3=uc3,u4=uc4,u5=uc5;
        const float mcv0=mcc0, mcv1=mcc1;

        // ============ stage A: state prop + tables + H (all lanes) ============
        float Rot_n[9], v_n[3], p_n[3], om[3], M1[9], M2[9];
        om[0]=u0-bw[0]; om[1]=u1-bw[1]; om[2]=u2-bw[2];
        {
            const float ai0=u3-ba[0], ai1=u4-ba[1], ai2=u5-ba[2];
            const float ac0 = Rot[0]*ai0 + Rot[1]*ai1 + Rot[2]*ai2;
            const float ac1 = Rot[3]*ai0 + Rot[4]*ai1 + Rot[5]*ai2;
            const float ac2 = Rot[6]*ai0 + Rot[7]*ai1 + Rot[8]*ai2 - GRAV;
            v_n[0]=vv[0]+ac0*dt; v_n[1]=vv[1]+ac1*dt; v_n[2]=vv[2]+ac2*dt;
            p_n[0]=pp[0]+vv[0]*dt+0.5f*ac0*dt2;
            p_n[1]=pp[1]+vv[1]*dt+0.5f*ac1*dt2;
            p_n[2]=pp[2]+vv[2]*dt+0.5f*ac2*dt2;
            float E[9]; so3exp_dev(om[0]*dt, om[1]*dt, om[2]*dt, E);
            m3mul_dev(Rot, E, Rot_n);
        }
#pragma unroll
        for (int c=0;c<3;c++) {
            M1[0+c] = -vv[2]*Rot[3+c] + vv[1]*Rot[6+c];
            M1[3+c] =  vv[2]*Rot[0+c] - vv[0]*Rot[6+c];
            M1[6+c] = -vv[1]*Rot[0+c] + vv[0]*Rot[3+c];
            M2[0+c] = -pp[2]*Rot[3+c] + pp[1]*Rot[6+c];
            M2[3+c] =  pp[2]*Rot[0+c] - pp[0]*Rot[6+c];
            M2[6+c] = -pp[1]*Rot[0+c] + pp[0]*Rot[3+c];
        }
        const float hdt2 = 0.5f*dt2;
        const float sdt3 = dt*dt2*(1.0f/6.0f);
        const float dtg = dt*GRAV, hg = hdt2*GRAV;

        // rows table: sRows[i][c] = (i<3?Rot : i<6?M1 : M2)[(i%3)*3+c]
        if (l < 27) {
            const int ri = l/3, c = l - 3*ri;
            const int rr = (ri<3) ? ri : ((ri<6) ? ri-3 : ri-6);
            const float rotv = sel3f(c, sel3f(rr,Rot[0],Rot[3],Rot[6]),
                                        sel3f(rr,Rot[1],Rot[4],Rot[7]),
                                        sel3f(rr,Rot[2],Rot[5],Rot[8]));
            const float m1v  = sel3f(c, sel3f(rr,M1[0],M1[3],M1[6]),
                                        sel3f(rr,M1[1],M1[4],M1[7]),
                                        sel3f(rr,M1[2],M1[5],M1[8]));
            const float m2v  = sel3f(c, sel3f(rr,M2[0],M2[3],M2[6]),
                                        sel3f(rr,M2[1],M2[4],M2[7]),
                                        sel3f(rr,M2[2],M2[5],M2[8]));
            sRows[ri*4 + c] = (ri<3) ? rotv : ((ri<6) ? m1v : m2v);
        }
        // Phi coeff table rows 0..8: [i][0..2]=cbw, [3..5]=cba
        if (l < 54) {
            const int ri = l/6, c6 = l - 6*ri;
            const int cc = (c6 < 3) ? c6 : c6-3;
            const int rr = ri - 3*(ri/3), br = ri/3;
            const float m0r = sel3f(cc, sel3f(rr,Rot[0],Rot[3],Rot[6]),
                                        sel3f(rr,Rot[1],Rot[4],Rot[7]),
                                        sel3f(rr,Rot[2],Rot[5],Rot[8]));
            const float m1r = sel3f(cc, sel3f(rr,M1[0],M1[3],M1[6]),
                                        sel3f(rr,M1[1],M1[4],M1[7]),
                                        sel3f(rr,M1[2],M1[5],M1[8]));
            const float m2r = sel3f(cc, sel3f(rr,M2[0],M2[3],M2[6]),
                                        sel3f(rr,M2[1],M2[4],M2[7]),
                                        sel3f(rr,M2[2],M2[5],M2[8]));
            const float sgm = sel3f(rr, GRAV*sel3f(cc,Rot[3],Rot[4],Rot[5]),
                                        -GRAV*sel3f(cc,Rot[0],Rot[1],Rot[2]), 0.f);
            float cbwv, cbav;
            if (br == 0)      { cbwv = -dt*m0r;                       cbav = 0.f; }
            else if (br == 1) { cbwv = -dt*m1r - hdt2*sgm;            cbav = -dt*m0r; }
            else              { cbwv = -dt*m2r - hdt2*m1r - sdt3*sgm; cbav = -hdt2*m0r; }
            sPhiB[ri*8 + c6] = (c6 < 3) ? cbwv : cbav;
        }
        // measurement H + residual (values computed in all lanes; lanes<42 write)
        {
            float Rb[9]; m3mul_dev(Rot_n, Rci, Rb);
            const float vi0 = Rot_n[0]*v_n[0] + Rot_n[3]*v_n[1] + Rot_n[6]*v_n[2];
            const float vi1 = Rot_n[1]*v_n[0] + Rot_n[4]*v_n[1] + Rot_n[7]*v_n[2];
            const float vi2 = Rot_n[2]*v_n[0] + Rot_n[5]*v_n[1] + Rot_n[8]*v_n[2];
            float Hv1[3], Hv2[3];
            Hv1[0] =  Rci[4]*vi2 - Rci[7]*vi1;
            Hv1[1] = -Rci[1]*vi2 + Rci[7]*vi0;
            Hv1[2] =  Rci[1]*vi1 - Rci[4]*vi0;
            Hv2[0] =  Rci[5]*vi2 - Rci[8]*vi1;
            Hv2[1] = -Rci[2]*vi2 + Rci[8]*vi0;
            Hv2[2] =  Rci[2]*vi1 - Rci[5]*vi0;
            const float vb1 = Rci[1]*vi0 + Rci[4]*vi1 + Rci[7]*vi2 + (tci[2]*om[0] - tci[0]*om[2]);
            const float vb2 = Rci[2]*vi0 + Rci[5]*vi1 + Rci[8]*vi2 + (tci[0]*om[1] - tci[1]*om[0]);
            if (l < 42) {
                const int a  = l / 21;
                const int jj = l - 21*a;
                const int bj = jj / 3;
                const int rj = jj - 3*bj;
                float val = 0.f;
                if (bj == 1) {
                    val = (a==0) ? sel3f(rj, Rb[1], Rb[4], Rb[7])
                                 : sel3f(rj, Rb[2], Rb[5], Rb[8]);
                } else if (bj == 3) {
                    val = (a==0) ? sel3f(rj, tci[2], 0.f, -tci[0])
                                 : sel3f(rj, -tci[1], tci[0], 0.f);
                } else if (bj == 5) {
                    val = (a==0) ? sel3f(rj, Hv1[0], Hv1[1], Hv1[2])
                                 : sel3f(rj, Hv2[0], Hv2[1], Hv2[2]);
                } else if (bj == 6) {
                    val = (a==0) ? sel3f(rj, -om[2], 0.f, om[0])
                                 : sel3f(rj, om[1], -om[0], 0.f);
                }
                sH[a*SP + jj] = val;
            }
            if (l == 0) { sr[0] = -vb1; sr[1] = -vb2; }
        }
        __syncthreads();   // 64-thread workgroup: lowers to waitcnt only

        // ============ A = P + G Q G^T ============
        float Areg[7];
#pragma unroll
        for (int q = 0; q < 7; ++q) {
            float Wij = 0.f;
            if (gq[q]) {
                const float4 mav = *(const float4*)&sRows[ei[q]*4];
                const float4 mbv = *(const float4*)&sRows[ej[q]*4];
                Wij = dt2*Q0c*(mav.x*mbv.x + mav.y*mbv.y + mav.z*mbv.z);
                if (ei[q] >= 3 && ei[q] < 6 && ej[q] >= 3 && ej[q] < 6) {
                    const int ri = ei[q]-3, rj = ej[q]-3;
                    const float ra0=sel3f(ri,Rot[0],Rot[3],Rot[6]), ra1=sel3f(ri,Rot[1],Rot[4],Rot[7]), ra2=sel3f(ri,Rot[2],Rot[5],Rot[8]);
                    const float rb0=sel3f(rj,Rot[0],Rot[3],Rot[6]), rb1=sel3f(rj,Rot[1],Rot[4],Rot[7]), rb2=sel3f(rj,Rot[2],Rot[5],Rot[8]);
                    Wij += dt2*Q1c*(ra0*rb0 + ra1*rb1 + ra2*rb2);
                }
            } else if (ev[q] && ei[q] == ej[q] && ei[q] >= 9) {
                const float qd = (ei[q]<12) ? 6e-9f : (ei[q]<15) ? 2e-4f : 1e-9f;
                Wij = dt2*qd;
            }
            Areg[q] = Preg[q] + Wij;
            if (awr[q]) sA[eoff[q]] = Areg[q];
        }
        __syncthreads();

        // ============ T1 = Phi @ A (rows 0..8 only; rest identity) ============
        float T1reg[7];
#pragma unroll
        for (int q = 0; q < 7; ++q) {
            float tv = Areg[q];
            if (ev[q] && ei[q] < 9) {
                const int i = ei[q], j = ej[q];
                const int br = i/3, r = i - 3*br;
                const float4 pb0 = *(const float4*)&sPhiB[i*8];
                const float2 pb1 = *(const float2*)&sPhiB[i*8+4];
                if (br >= 1) {
                    const float a0 = sA[0*LDP+j], a1 = sA[1*LDP+j];
                    if (br == 1) tv += dtg * sel3f(r, a1, -a0, 0.f);
                    else { tv += hg * sel3f(r, a1, -a0, 0.f); tv += dt * sA[(3+r)*LDP+j]; }
                }
                tv += pb0.x*sA[ 9*LDP+j];
                tv += pb0.y*sA[10*LDP+j];
                tv += pb0.z*sA[11*LDP+j];
                if (br >= 1) {
                    tv += pb0.w*sA[12*LDP+j];
                    tv += pb1.x*sA[13*LDP+j];
                    tv += pb1.y*sA[14*LDP+j];
                }
            }
            T1reg[q] = tv;
            if (twr[q]) sT1[eoff[q]] = tv;
        }
        __syncthreads();

        // ============ Pn = T1 @ Phi^T (cols 0..8 only) ============
        float Pnreg[7];
#pragma unroll
        for (int q = 0; q < 7; ++q) {
            float pv = T1reg[q];
            if (ev[q] && ej[q] < 9) {
                const int i = ei[q], j = ej[q];
                const int br = j/3, r = j - 3*br;
                const int rb = i*LDP;
                const float4 pb0 = *(const float4*)&sPhiB[j*8];
                const float2 pb1 = *(const float2*)&sPhiB[j*8+4];
                if (br >= 1) {
                    const float b0 = sT1[rb+0], b1 = sT1[rb+1];
                    if (br == 1) pv += dtg * sel3f(r, b1, -b0, 0.f);
                    else { pv += hg * sel3f(r, b1, -b0, 0.f); pv += dt * sT1[rb+3+r]; }
                }
                pv += pb0.x*sT1[rb+ 9];
                pv += pb0.y*sT1[rb+10];
                pv += pb0.z*sT1[rb+11];
                if (br >= 1) {
                    pv += pb0.w*sT1[rb+12];
                    pv += pb1.x*sT1[rb+13];
                    pv += pb1.y*sT1[rb+14];
                }
            }
            Pnreg[q] = pv;
            if (ev[q]) sPn[eoff[q]] = pv;
        }
        __syncthreads();

        // ============ HP = H@Pn, HPT = H@Pn^T (lanes 0..41) ============
        if (l < 42) {
            const int a = l/21, jj = l - 21*a;
            const int hix[12] = {3,4,5,9,10,11,15,16,17,18,19,20};
            float hp = 0.f, ht = 0.f;
#pragma unroll
            for (int q2=0;q2<12;q2++) hp += sH[a*SP + hix[q2]] * sPn[hix[q2]*LDP + jj];
#pragma unroll
            for (int q2=0;q2<12;q2++) ht += sH[a*SP + hix[q2]] * sPn[jj*LDP + hix[q2]];
            sHpack[jj*4 + a]     = hp;
            sHpack[jj*4 + 2 + a] = ht;
        }
        __syncthreads();

        // ============ S = HP @ H^T + Rm (lanes 0..3) ============
        if (l < 4) {
            const int a = l >> 1, b = l & 1;
            float acc = 0.f;
#pragma unroll
            for (int jj=0;jj<21;jj++) acc += sHpack[jj*4 + a] * sH[b*SP + jj];
            if (l == 0) acc += mcv0;
            if (l == 3) acc += mcv1;
            sS[l] = acc;
        }
        __syncthreads();

        // ============ 2x2 pivoted solve, K, KS, dx (lanes 0..20) ============
        if (l < 21) {
            const float S00 = sS[0], S01 = sS[1], S10 = sS[2], S11 = sS[3];
            const float b0 = sHpack[l*4+2], b1 = sHpack[l*4+3];
            float x0, x1;
            if (fabsf(S00) >= fabsf(S10)) {
                const float fac = S10/S00;
                x1 = (b1 - fac*b0) / (S11 - fac*S01);
                x0 = (b0 - S01*x1) / S00;
            } else {
                const float fac = S00/S10;
                x1 = (b0 - fac*b1) / (S01 - fac*S11);
                x0 = (b1 - S11*x1) / S10;
            }
            sKpack[l*4+0] = x0;
            sKpack[l*4+1] = x1;
            sKpack[l*4+2] = S00*x0 + S01*x1;
            sKpack[l*4+3] = S10*x0 + S11*x1;
            sdx[l] = x0*sr[0] + x1*sr[1];
        }
        __syncthreads();

        // ============ Joseph update (both orientations) + state update ============
#pragma unroll
        for (int q = 0; q < 7; ++q) {
            if (ev[q]) {
                const int i = ei[q], j = ej[q];
                const float4 Ki = *(const float4*)&sKpack[i*4];  // k0i,k1i,ks0i,ks1i
                const float4 Kj = *(const float4*)&sKpack[j*4];
                const float4 Hi = *(const float4*)&sHpack[i*4];  // hp0i,hp1i,ht0i,ht1i
                const float4 Hj = *(const float4*)&sHpack[j*4];
                const float pn_ij = Pnreg[q];
                const float pn_ji = sPn[j*LDP + i];
                const float puij = pn_ij - (Ki.x*Hj.x + Ki.y*Hj.y) - (Hi.z*Kj.x + Hi.w*Kj.y)
                                         + (Ki.x*Kj.z + Ki.y*Kj.w);
                const float puji = pn_ji - (Kj.x*Hi.x + Kj.y*Hi.y) - (Hj.z*Ki.x + Hj.w*Ki.y)
                                         + (Kj.x*Ki.z + Kj.y*Ki.w);
                Preg[q] = 0.5f*(puij + puji);
            }
        }
        {
            float dxr[21];
#pragma unroll
            for (int q2=0;q2<6;q2++){
                const float4 x = *(const float4*)(&sdx[4*q2]);
                dxr[4*q2] = x.x;
                if (4*q2+1 < 21) dxr[4*q2+1] = x.y;
                if (4*q2+2 < 21) dxr[4*q2+2] = x.z;
                if (4*q2+3 < 21) dxr[4*q2+3] = x.w;
            }
            float dR[9], Jm[9];
            const float q0 = dxr[0], q1 = dxr[1], q2 = dxr[2];
            const float sq = q0*q0 + q1*q1 + q2*q2;
            if (sq < 1e-16f) {
                dR[0]=1.f; dR[1]=-q2; dR[2]=q1;
                dR[3]=q2;  dR[4]=1.f; dR[5]=-q0;
                dR[6]=-q1; dR[7]=q0;  dR[8]=1.f;
                Jm[0]=1.f;      Jm[1]=-0.5f*q2; Jm[2]=0.5f*q1;
                Jm[3]=0.5f*q2;  Jm[4]=1.f;      Jm[5]=-0.5f*q0;
                Jm[6]=-0.5f*q1; Jm[7]=0.5f*q0;  Jm[8]=1.f;
            } else {
                const float ang = sqrtf(sq);
                const float ax=q0/ang, ay=q1/ang, az=q2/ang;
                const float s=sinf(ang), c=cosf(ang), o=1.f-c;
                dR[0]=c+o*ax*ax;    dR[1]=o*ax*ay-s*az; dR[2]=o*ax*az+s*ay;
                dR[3]=o*ay*ax+s*az; dR[4]=c+o*ay*ay;    dR[5]=o*ay*az-s*ax;
                dR[6]=o*az*ax-s*ay; dR[7]=o*az*ay+s*ax; dR[8]=c+o*az*az;
                const float sa  = s/ang;
                const float osa = 1.f - sa;
                const float tt  = o/ang;
                Jm[0]=sa+osa*ax*ax;    Jm[1]=osa*ax*ay-tt*az; Jm[2]=osa*ax*az+tt*ay;
                Jm[3]=osa*ay*ax+tt*az; Jm[4]=sa+osa*ay*ay;    Jm[5]=osa*ay*az-tt*ax;
                Jm[6]=osa*az*ax-tt*ay; Jm[7]=osa*az*ay+tt*ax; Jm[8]=sa+osa*az*az;
            }
            float nR[9]; m3mul_dev(dR, Rot_n, nR);
#pragma unroll
            for (int c=0;c<9;c++) Rot[c] = nR[c];
            const float dv0 = Jm[0]*dxr[3] + Jm[1]*dxr[4] + Jm[2]*dxr[5];
            const float dv1 = Jm[3]*dxr[3] + Jm[4]*dxr[4] + Jm[5]*dxr[5];
            const float dv2 = Jm[6]*dxr[3] + Jm[7]*dxr[4] + Jm[8]*dxr[5];
            const float dp0 = Jm[0]*dxr[6] + Jm[1]*dxr[7] + Jm[2]*dxr[8];
            const float dp1 = Jm[3]*dxr[6] + Jm[4]*dxr[7] + Jm[5]*dxr[8];
            const float dp2 = Jm[6]*dxr[6] + Jm[7]*dxr[7] + Jm[8]*dxr[8];
            const float nv0 = dR[0]*v_n[0] + dR[1]*v_n[1] + dR[2]*v_n[2] + dv0;
            const float nv1 = dR[3]*v_n[0] + dR[4]*v_n[1] + dR[5]*v_n[2] + dv1;
            const float nv2 = dR[6]*v_n[0] + dR[7]*v_n[1] + dR[8]*v_n[2] + dv2;
            const float np0 = dR[0]*p_n[0] + dR[1]*p_n[1] + dR[2]*p_n[2] + dp0;
            const float np1 = dR[3]*p_n[0] + dR[4]*p_n[1] + dR[5]*p_n[2] + dp1;
            const float np2v= dR[6]*p_n[0] + dR[7]*p_n[1] + dR[8]*p_n[2] + dp2;
            vv[0]=nv0; vv[1]=nv1; vv[2]=nv2;
            pp[0]=np0; pp[1]=np1; pp[2]=np2v;
            bw[0]+=dxr[9];  bw[1]+=dxr[10]; bw[2]+=dxr[11];
            ba[0]+=dxr[12]; ba[1]+=dxr[13]; ba[2]+=dxr[14];
            float E2[9]; so3exp_dev(dxr[15], dxr[16], dxr[17], E2);
            float nRc[9]; m3mul_dev(E2, Rci, nRc);
#pragma unroll
            for (int c=0;c<9;c++) Rci[c] = nRc[c];
            tci[0]+=dxr[18]; tci[1]+=dxr[19]; tci[2]+=dxr[20];
        }
        STORE_TRAJ(n+1);

        // ---- rotate software pipeline ----
        t_cur = tn_c;
        tn_c  = tn_n;
        uc0=un0; uc1=un1; uc2=un2; uc3=un3; uc4=un4; uc5=un5;
        mcc0=mcn0; mcc1=mcn1;
        // No trailing sync: next stage-A writes (sRows/sPhiB/sH/sr) have their
        // last readers >=1 syncthreads upstream within this iteration.
    }
}

extern "C" void kernel_launch(void* const* d_in, const int* in_sizes, int n_in,
                              void* d_out, int out_size, void* d_ws, size_t ws_size,
                              hipStream_t stream) {
    const float* t     = (const float*)d_in[0];
    const float* u     = (const float*)d_in[1];
    const float* mc    = (const float*)d_in[2];
    const float* v_mes = (const float*)d_in[3];
    const float* ang0  = (const float*)d_in[5];
    float* out = (float*)d_out;
    const int N = in_sizes[0];
    (void)d_ws; (void)ws_size; (void)n_in; (void)out_size;
    iekf_scan_kernel<<<1, 64, 0, stream>>>(t, u, mc, v_mes, ang0, out, N);
}

// Round 7
// 202372.229 us; speedup vs baseline: 1.3906x; 1.3906x over previous
//
#include <hip/hip_runtime.h>
#include <math.h>

// Invariant-EKF sequential scan, SINGLE WAVE (64 lanes), batched-LDS edition.
// Round-6 post-mortem: ~90% stall = scattered scalar ds_reads under divergent
// guards paying ~120cyc each, serially. This version makes every phase
// branchless with contiguous ds_read_b128 row reads (dual row/col layouts),
// a uniform Phi-coefficient table (zero rows pad), in-register H (no sH),
// and raw "s_waitcnt lgkmcnt(0)" syncs (no s_barrier, no vmcnt drain).
// All arithmetic preserves the passing kernel's operand order (mod +-0 terms).

#define GRAV 9.80665f
#define P24 24   // matrix row pitch (floats), rows 16B-aligned (96B)
#define PC  12   // sPhiC row pitch
#define Q0c 0.001f
#define Q1c 0.01f

#define WSYNC() asm volatile("s_waitcnt lgkmcnt(0)" ::: "memory")

__device__ __forceinline__ float sel3f(int r, float a, float b, float c) {
    return (r == 0) ? a : ((r == 1) ? b : c);
}

__device__ __forceinline__ void m3mul_dev(const float* A, const float* B, float* C) {
#pragma unroll
    for (int i = 0; i < 3; ++i) {
#pragma unroll
        for (int j = 0; j < 3; ++j) {
            C[i*3+j] = A[i*3+0]*B[j] + A[i*3+1]*B[3+j] + A[i*3+2]*B[6+j];
        }
    }
}

__device__ __forceinline__ void so3exp_dev(float p0, float p1, float p2, float* R) {
    float sq = p0*p0 + p1*p1 + p2*p2;
    if (sq < 1e-16f) {
        R[0]=1.f;  R[1]=-p2;  R[2]=p1;
        R[3]=p2;   R[4]=1.f;  R[5]=-p0;
        R[6]=-p1;  R[7]=p0;   R[8]=1.f;
    } else {
        float ang = sqrtf(sq);
        float ax=p0/ang, ay=p1/ang, az=p2/ang;
        float s=sinf(ang), c=cosf(ang), o=1.f-c;
        R[0]=c+o*ax*ax;    R[1]=o*ax*ay-s*az; R[2]=o*ax*az+s*ay;
        R[3]=o*ay*ax+s*az; R[4]=c+o*ay*ay;    R[5]=o*ay*az-s*ax;
        R[6]=o*az*ax-s*ay; R[7]=o*az*ay+s*ax; R[8]=c+o*az*az;
    }
}

// lanes 0..32 write the 33 trajectory scalars for row NIDX
#define STORE_TRAJ(NIDX)                                                        \
    do {                                                                        \
        if (l < 33) {                                                           \
            float val = Rot[0];                                                 \
            if (l==1) val=Rot[1];  if (l==2) val=Rot[2];                        \
            if (l==3) val=Rot[3];  if (l==4) val=Rot[4];                        \
            if (l==5) val=Rot[5];  if (l==6) val=Rot[6];                        \
            if (l==7) val=Rot[7];  if (l==8) val=Rot[8];                        \
            if (l==9)  val=vv[0];  if (l==10) val=vv[1];  if (l==11) val=vv[2]; \
            if (l==12) val=pp[0];  if (l==13) val=pp[1];  if (l==14) val=pp[2]; \
            if (l==15) val=bw[0];  if (l==16) val=bw[1];  if (l==17) val=bw[2]; \
            if (l==18) val=ba[0];  if (l==19) val=ba[1];  if (l==20) val=ba[2]; \
            if (l==21) val=Rci[0]; if (l==22) val=Rci[1]; if (l==23) val=Rci[2];\
            if (l==24) val=Rci[3]; if (l==25) val=Rci[4]; if (l==26) val=Rci[5];\
            if (l==27) val=Rci[6]; if (l==28) val=Rci[7]; if (l==29) val=Rci[8];\
            if (l==30) val=tci[0]; if (l==31) val=tci[1]; if (l==32) val=tci[2];\
            out[ob + os_ * (NIDX) + orr] = val;                                 \
        }                                                                       \
    } while (0)

__global__ __launch_bounds__(64, 1)
void iekf_scan_kernel(const float* __restrict__ t,
                      const float* __restrict__ u,
                      const float* __restrict__ mc,
                      const float* __restrict__ v_mes,
                      const float* __restrict__ ang0,
                      float* __restrict__ out,
                      const int N)
{
    __shared__ __align__(16) float sRows[10*4];     // GQGT rows: 0-2 Rot, 3-5 M1, 6-8 M2 (row 9 garbage pad)
    __shared__ __align__(16) float sPhiC[21*PC];    // per-row Phi coeffs; rows 9..20 zero
    __shared__ __align__(16) float sAT [22*P24];    // A transposed (row j holds A[:,j]); row 21 = dump
    __shared__ __align__(16) float sT1 [22*P24];    // T1 row-major; row 21 = dump
    __shared__ __align__(16) float sPn [22*P24];    // Pn row-major
    __shared__ __align__(16) float sPnT[22*P24];    // Pn transposed
    __shared__ __align__(16) float sHpack[21*4];    // (hp0,hp1,ht0,ht1) per column
    __shared__ __align__(16) float sKpack[21*4];    // (k0,k1,ks0,ks1) per row
    __shared__ __align__(16) float sdx[24];

    const int l = (int)threadIdx.x;

    // ---- per-lane element map: e = 64q + l -> (i,j); invalid -> clamped reads, dump writes
    int ei[7], ej[7], wro[7], wco[7];
    bool ev[7];
#pragma unroll
    for (int q = 0; q < 7; ++q) {
        const int e = 64*q + l;
        const bool v = (e < 441);
        const int ii = e / 21;
        const int jj = e - ii*21;
        ev[q] = v;
        ei[q] = v ? ii : 20;
        ej[q] = v ? jj : 20;
        wro[q] = (v ? ii : 21)*P24 + ej[q];   // row-major write offset (dump row 21)
        wco[q] = (v ? jj : 21)*P24 + ei[q];   // col-major write offset
    }

    // ---- small state (replicated in all lanes) ----
    float Rot[9], vv[3], pp[3], bw[3], ba[3], Rci[9], tci[3];
    {
        const float roll = ang0[0], pitch = ang0[1], yaw = ang0[2];
        const float cr = cosf(roll),  srl = sinf(roll);
        const float cp = cosf(pitch), spt = sinf(pitch);
        const float cy = cosf(yaw),   syw = sinf(yaw);
        float rx[9] = {1.f,0.f,0.f, 0.f,cr,-srl, 0.f,srl,cr};
        float ry[9] = {cp,0.f,spt, 0.f,1.f,0.f, -spt,0.f,cp};
        float rz[9] = {cy,-syw,0.f, syw,cy,0.f, 0.f,0.f,1.f};
        float tm[9]; m3mul_dev(rz, ry, tm);
        m3mul_dev(tm, rx, Rot);
        vv[0]=v_mes[0]; vv[1]=v_mes[1]; vv[2]=v_mes[2];
#pragma unroll
        for (int c=0;c<3;c++){ pp[c]=0.f; bw[c]=0.f; ba[c]=0.f; tci[c]=0.f; }
        Rci[0]=1.f;Rci[1]=0.f;Rci[2]=0.f;Rci[3]=0.f;Rci[4]=1.f;Rci[5]=0.f;
        Rci[6]=0.f;Rci[7]=0.f;Rci[8]=1.f;
    }

    // ---- P diag init ----
    float Preg[7];
#pragma unroll
    for (int q = 0; q < 7; ++q) {
        float pd = 0.f;
        if (ev[q] && ei[q] == ej[q]) {
            const int ii = ei[q];
            if (ii==0 || ii==1)        pd = 0.001f;
            else if (ii==3 || ii==4)   pd = 0.1f;
            else if (ii>=9  && ii<12)  pd = 0.006f;
            else if (ii>=12 && ii<15)  pd = 0.004f;
            else if (ii>=15 && ii<18)  pd = 1e-6f;
            else if (ii>=18)           pd = 0.005f;
        }
        Preg[q] = pd;
    }

    // ---- output address constants ----
    int ob=0, os_=0, orr=0;
    if (l<33) {
        if (l<9)       { ob = 0;    os_ = 9; orr = l;    }
        else if (l<12) { ob = 9*N;  os_ = 3; orr = l-9;  }
        else if (l<15) { ob = 12*N; os_ = 3; orr = l-12; }
        else if (l<18) { ob = 15*N; os_ = 3; orr = l-15; }
        else if (l<21) { ob = 18*N; os_ = 3; orr = l-18; }
        else if (l<30) { ob = 21*N; os_ = 9; orr = l-21; }
        else           { ob = 30*N; os_ = 3; orr = l-30; }
    }

    STORE_TRAJ(0);

    float t_cur = t[0];

    // ---- software-pipelined inputs ----
    float tn_c = t[1];
    float uc0,uc1,uc2,uc3,uc4,uc5;
    { const float* un = u + 6; uc0=un[0]; uc1=un[1]; uc2=un[2]; uc3=un[3]; uc4=un[4]; uc5=un[5]; }
    float mcc0 = mc[2], mcc1 = mc[3];

    for (int n = 0; n < N-1; ++n) {
        const int np2 = (n+2 < N) ? (n+2) : (N-1);
        const float tn_n = t[np2];
        float un0,un1,un2,un3,un4,un5;
        { const float* un = u + (size_t)np2*6; un0=un[0]; un1=un[1]; un2=un[2]; un3=un[3]; un4=un[4]; un5=un[5]; }
        const float mcn0 = mc[2*np2], mcn1 = mc[2*np2+1];

        const float dt  = tn_c - t_cur;
        const float dt2 = dt*dt;
        const float u0=uc0,u1=uc1,u2=uc2,u3=uc3,u4=uc4,u5=uc5;
        const float mcv0=mcc0, mcv1=mcc1;

        // ================= stage A: state prop, tables, in-register H =================
        float Rot_n[9], v_n[3], p_n[3], om[3], M1[9], M2[9];
        om[0]=u0-bw[0]; om[1]=u1-bw[1]; om[2]=u2-bw[2];
        {
            const float ai0=u3-ba[0], ai1=u4-ba[1], ai2=u5-ba[2];
            const float ac0 = Rot[0]*ai0 + Rot[1]*ai1 + Rot[2]*ai2;
            const float ac1 = Rot[3]*ai0 + Rot[4]*ai1 + Rot[5]*ai2;
            const float ac2 = Rot[6]*ai0 + Rot[7]*ai1 + Rot[8]*ai2 - GRAV;
            v_n[0]=vv[0]+ac0*dt; v_n[1]=vv[1]+ac1*dt; v_n[2]=vv[2]+ac2*dt;
            p_n[0]=pp[0]+vv[0]*dt+0.5f*ac0*dt2;
            p_n[1]=pp[1]+vv[1]*dt+0.5f*ac1*dt2;
            p_n[2]=pp[2]+vv[2]*dt+0.5f*ac2*dt2;
            float E[9]; so3exp_dev(om[0]*dt, om[1]*dt, om[2]*dt, E);
            m3mul_dev(Rot, E, Rot_n);
        }
#pragma unroll
        for (int c=0;c<3;c++) {
            M1[0+c] = -vv[2]*Rot[3+c] + vv[1]*Rot[6+c];
            M1[3+c] =  vv[2]*Rot[0+c] - vv[0]*Rot[6+c];
            M1[6+c] = -vv[1]*Rot[0+c] + vv[0]*Rot[3+c];
            M2[0+c] = -pp[2]*Rot[3+c] + pp[1]*Rot[6+c];
            M2[3+c] =  pp[2]*Rot[0+c] - pp[0]*Rot[6+c];
            M2[6+c] = -pp[1]*Rot[0+c] + pp[0]*Rot[3+c];
        }
        const float hdt2 = 0.5f*dt2;
        const float sdt3 = dt*dt2*(1.0f/6.0f);
        const float dtg = dt*GRAV, hg = hdt2*GRAV;

        // GQGT rows table (lanes 0..26)
        if (l < 27) {
            const int ri = l/3, c = l - 3*ri;
            const int rr = (ri<3) ? ri : ((ri<6) ? ri-3 : ri-6);
            const float rotv = sel3f(c, sel3f(rr,Rot[0],Rot[3],Rot[6]),
                                        sel3f(rr,Rot[1],Rot[4],Rot[7]),
                                        sel3f(rr,Rot[2],Rot[5],Rot[8]));
            const float m1v  = sel3f(c, sel3f(rr,M1[0],M1[3],M1[6]),
                                        sel3f(rr,M1[1],M1[4],M1[7]),
                                        sel3f(rr,M1[2],M1[5],M1[8]));
            const float m2v  = sel3f(c, sel3f(rr,M2[0],M2[3],M2[6]),
                                        sel3f(rr,M2[1],M2[4],M2[7]),
                                        sel3f(rr,M2[2],M2[5],M2[8]));
            sRows[ri*4 + c] = (ri<3) ? rotv : ((ri<6) ? m1v : m2v);
        }
        // Phi coefficient table, 21 rows (rows >=9 all zero).  Layout per row:
        // [0..2]=cbw, [3..5]=cba, [6]=ca0, [7]=ca1, [8..10]=cv, [11]=0
        if (l < 21) {
            const int j = l, br = j/3, r = j - 3*br;
            float cf[12];
#pragma unroll
            for (int c=0;c<3;c++) {
                const float m0r = sel3f(r, Rot[0+c], Rot[3+c], Rot[6+c]);
                const float m1r = sel3f(r, M1[0+c], M1[3+c], M1[6+c]);
                const float m2r = sel3f(r, M2[0+c], M2[3+c], M2[6+c]);
                const float sgm = sel3f(r, GRAV*Rot[3+c], -GRAV*Rot[0+c], 0.f);
                cf[0+c] = (br==0) ? (-dt*m0r)
                        : (br==1) ? (-dt*m1r - hdt2*sgm)
                        : (br==2) ? (-dt*m2r - hdt2*m1r - sdt3*sgm) : 0.f;
                cf[3+c] = (br==1) ? (-dt*m0r) : (br==2) ? (-hdt2*m0r) : 0.f;
                cf[8+c] = (br==2 && r==c) ? dt : 0.f;
            }
            cf[6] = (br==1) ? ((r==1)? -dtg : 0.f) : (br==2) ? ((r==1)? -hg : 0.f) : 0.f;
            cf[7] = (br==1) ? ((r==0)?  dtg : 0.f) : (br==2) ? ((r==0)?  hg : 0.f) : 0.f;
            cf[11] = 0.f;
            float4 w0; w0.x=cf[0]; w0.y=cf[1]; w0.z=cf[2]; w0.w=cf[3];
            float4 w1; w1.x=cf[4]; w1.y=cf[5]; w1.z=cf[6]; w1.w=cf[7];
            float4 w2; w2.x=cf[8]; w2.y=cf[9]; w2.z=cf[10]; w2.w=cf[11];
            *(float4*)&sPhiC[j*PC+0] = w0;
            *(float4*)&sPhiC[j*PC+4] = w1;
            *(float4*)&sPhiC[j*PC+8] = w2;
        }

        // in-register H (all lanes) + residual
        float H0_3,H0_4,H0_5,H1_3,H1_4,H1_5,H0_9,H0_10,H0_11,H1_9,H1_10,H1_11;
        float H0_15,H0_16,H0_17,H1_15,H1_16,H1_17,H0_18,H0_19,H0_20,H1_18,H1_19,H1_20;
        float r0s, r1s;
        {
            float Rb[9]; m3mul_dev(Rot_n, Rci, Rb);
            const float vi0 = Rot_n[0]*v_n[0] + Rot_n[3]*v_n[1] + Rot_n[6]*v_n[2];
            const float vi1 = Rot_n[1]*v_n[0] + Rot_n[4]*v_n[1] + Rot_n[7]*v_n[2];
            const float vi2 = Rot_n[2]*v_n[0] + Rot_n[5]*v_n[1] + Rot_n[8]*v_n[2];
            H0_3 = Rb[1]; H0_4 = Rb[4]; H0_5 = Rb[7];
            H1_3 = Rb[2]; H1_4 = Rb[5]; H1_5 = Rb[8];
            H0_9 = tci[2]; H0_10 = 0.f; H0_11 = -tci[0];
            H1_9 = -tci[1]; H1_10 = tci[0]; H1_11 = 0.f;
            H0_15 =  Rci[4]*vi2 - Rci[7]*vi1;
            H0_16 = -Rci[1]*vi2 + Rci[7]*vi0;
            H0_17 =  Rci[1]*vi1 - Rci[4]*vi0;
            H1_15 =  Rci[5]*vi2 - Rci[8]*vi1;
            H1_16 = -Rci[2]*vi2 + Rci[8]*vi0;
            H1_17 =  Rci[2]*vi1 - Rci[5]*vi0;
            H0_18 = -om[2]; H0_19 = 0.f; H0_20 = om[0];
            H1_18 = om[1];  H1_19 = -om[0]; H1_20 = 0.f;
            const float vb1 = Rci[1]*vi0 + Rci[4]*vi1 + Rci[7]*vi2 + (tci[2]*om[0] - tci[0]*om[2]);
            const float vb2 = Rci[2]*vi0 + Rci[5]*vi1 + Rci[8]*vi2 + (tci[0]*om[1] - tci[1]*om[0]);
            r0s = -vb1; r1s = -vb2;
        }
        WSYNC();                        // (1) sRows/sPhiC visible

        // ================= A = P + G Q G^T  (write A^T only) =================
        float Areg[7];
#pragma unroll
        for (int q = 0; q < 7; ++q) {
            float Wij;
            if (q <= 2) {               // compile-time: all i<9 elements live in q 0..2
                const bool gqv = (ei[q] < 9) && (ej[q] < 9);
                const int ra_r = (ei[q] < 9) ? ei[q] : 9;
                const int rb_r = (ej[q] < 9) ? ej[q] : 9;
                const float4 ra = *(const float4*)&sRows[ra_r*4];
                const float4 rb = *(const float4*)&sRows[rb_r*4];
                float w = dt2*Q0c*(ra.x*rb.x + ra.y*rb.y + ra.z*rb.z);
                const int ri = ei[q]-3, rj = ej[q]-3;
                const float ra0=sel3f(ri,Rot[0],Rot[3],Rot[6]), ra1=sel3f(ri,Rot[1],Rot[4],Rot[7]), ra2=sel3f(ri,Rot[2],Rot[5],Rot[8]);
                const float rb0=sel3f(rj,Rot[0],Rot[3],Rot[6]), rb1=sel3f(rj,Rot[1],Rot[4],Rot[7]), rb2=sel3f(rj,Rot[2],Rot[5],Rot[8]);
                const bool q1v = (ri>=0 && ri<3 && rj>=0 && rj<3);
                const float w2 = w + dt2*Q1c*(ra0*rb0 + ra1*rb1 + ra2*rb2);
                w = q1v ? w2 : w;
                Wij = gqv ? w : 0.f;
            } else {
                const bool dg = ev[q] && (ei[q] == ej[q]);
                const float qd = (ei[q]<12) ? 6e-9f : (ei[q]<15) ? 2e-4f : 1e-9f;
                Wij = dg ? dt2*qd : 0.f;
            }
            Areg[q] = Preg[q] + Wij;
            sAT[wco[q]] = Areg[q];
        }
        WSYNC();                        // (2) sAT visible

        // ================= T1 = Phi @ A  (rows 0..8 transform; write row-major) =================
        float T1reg[7];
#pragma unroll
        for (int q = 0; q < 7; ++q) {
            float tv = Areg[q];
            if (q <= 2) {
                const int co = ei[q]*PC;
                const float4 c0 = *(const float4*)&sPhiC[co];
                const float4 c1 = *(const float4*)&sPhiC[co+4];
                const float4 c2 = *(const float4*)&sPhiC[co+8];
                const int ro = ej[q]*P24;
                const float4 a0 = *(const float4*)&sAT[ro];
                const float4 a1 = *(const float4*)&sAT[ro+4];
                const float4 a2 = *(const float4*)&sAT[ro+8];
                const float4 a3 = *(const float4*)&sAT[ro+12];
                tv += c1.z*a0.x;   // ca0 * A[0][j]
                tv += c1.w*a0.y;   // ca1 * A[1][j]
                tv += c2.x*a0.w;   // cv0 * A[3][j]
                tv += c2.y*a1.x;   // cv1 * A[4][j]
                tv += c2.z*a1.y;   // cv2 * A[5][j]
                tv += c0.x*a2.y;   // cbw0 * A[9][j]
                tv += c0.y*a2.z;
                tv += c0.z*a2.w;
                tv += c0.w*a3.x;   // cba0 * A[12][j]
                tv += c1.x*a3.y;
                tv += c1.y*a3.z;
            }
            T1reg[q] = tv;
            sT1[wro[q]] = tv;
        }
        WSYNC();                        // (3) sT1 visible

        // ================= Pn = T1 @ Phi^T  (write both layouts) =================
        float Pnreg[7];
#pragma unroll
        for (int q = 0; q < 7; ++q) {
            const int co = ej[q]*PC;
            const float4 c0 = *(const float4*)&sPhiC[co];
            const float4 c1 = *(const float4*)&sPhiC[co+4];
            const float4 c2 = *(const float4*)&sPhiC[co+8];
            const int ro = ei[q]*P24;
            const float4 t0 = *(const float4*)&sT1[ro];
            const float4 t1 = *(const float4*)&sT1[ro+4];
            const float4 t2 = *(const float4*)&sT1[ro+8];
            const float4 t3 = *(const float4*)&sT1[ro+12];
            float pv = T1reg[q];
            pv += c1.z*t0.x;
            pv += c1.w*t0.y;
            pv += c2.x*t0.w;
            pv += c2.y*t1.x;
            pv += c2.z*t1.y;
            pv += c0.x*t2.y;
            pv += c0.y*t2.z;
            pv += c0.z*t2.w;
            pv += c0.w*t3.x;
            pv += c1.x*t3.y;
            pv += c1.y*t3.z;
            Pnreg[q] = pv;
            sPn [wro[q]] = pv;
            sPnT[wco[q]] = pv;
        }
        WSYNC();                        // (4) sPn/sPnT visible

        // ================= HP = H@Pn, HPT = H@Pn^T  (lanes 0..41 write) =================
        {
            const int a  = l / 21;
            const int jj = (l < 42) ? (l - 21*a) : 0;
            const int ro = jj*P24;
            const float4 p0 = *(const float4*)&sPnT[ro];
            const float4 p1 = *(const float4*)&sPnT[ro+4];
            const float4 p2 = *(const float4*)&sPnT[ro+8];
            const float4 p3 = *(const float4*)&sPnT[ro+12];
            const float4 p4 = *(const float4*)&sPnT[ro+16];
            const float4 p5 = *(const float4*)&sPnT[ro+20];
            const float4 q0 = *(const float4*)&sPn[ro];
            const float4 q1 = *(const float4*)&sPn[ro+4];
            const float4 q2 = *(const float4*)&sPn[ro+8];
            const float4 q3 = *(const float4*)&sPn[ro+12];
            const float4 q4 = *(const float4*)&sPn[ro+16];
            const float4 q5 = *(const float4*)&sPn[ro+20];
            const bool a0v = (a == 0);
            const float h3  = a0v ? H0_3  : H1_3,  h4  = a0v ? H0_4  : H1_4,  h5  = a0v ? H0_5  : H1_5;
            const float h9  = a0v ? H0_9  : H1_9,  h10 = a0v ? H0_10 : H1_10, h11 = a0v ? H0_11 : H1_11;
            const float h15 = a0v ? H0_15 : H1_15, h16 = a0v ? H0_16 : H1_16, h17 = a0v ? H0_17 : H1_17;
            const float h18 = a0v ? H0_18 : H1_18, h19 = a0v ? H0_19 : H1_19, h20 = a0v ? H0_20 : H1_20;
            float hp = 0.f;
            hp += h3*p0.w;  hp += h4*p1.x;  hp += h5*p1.y;
            hp += h9*p2.y;  hp += h10*p2.z; hp += h11*p2.w;
            hp += h15*p3.w; hp += h16*p4.x; hp += h17*p4.y;
            hp += h18*p4.z; hp += h19*p4.w; hp += h20*p5.x;
            float ht = 0.f;
            ht += h3*q0.w;  ht += h4*q1.x;  ht += h5*q1.y;
            ht += h9*q2.y;  ht += h10*q2.z; ht += h11*q2.w;
            ht += h15*q3.w; ht += h16*q4.x; ht += h17*q4.y;
            ht += h18*q4.z; ht += h19*q4.w; ht += h20*q5.x;
            if (l < 42) {
                sHpack[jj*4 + a]     = hp;
                sHpack[jj*4 + 2 + a] = ht;
            }
        }
        WSYNC();                        // (5) sHpack visible

        // ================= S (all lanes, redundant) + solve/K/dx (lanes 0..20) ================
        {
            const float4 v3  = *(const float4*)&sHpack[3*4];
            const float4 v4  = *(const float4*)&sHpack[4*4];
            const float4 v5  = *(const float4*)&sHpack[5*4];
            const float4 v9  = *(const float4*)&sHpack[9*4];
            const float4 v10 = *(const float4*)&sHpack[10*4];
            const float4 v11 = *(const float4*)&sHpack[11*4];
            const float4 v15 = *(const float4*)&sHpack[15*4];
            const float4 v16 = *(const float4*)&sHpack[16*4];
            const float4 v17 = *(const float4*)&sHpack[17*4];
            const float4 v18 = *(const float4*)&sHpack[18*4];
            const float4 v19 = *(const float4*)&sHpack[19*4];
            const float4 v20 = *(const float4*)&sHpack[20*4];
            float S00 = 0.f, S01 = 0.f, S10 = 0.f, S11 = 0.f;
            S00 += v3.x*H0_3;  S00 += v4.x*H0_4;  S00 += v5.x*H0_5;
            S00 += v9.x*H0_9;  S00 += v10.x*H0_10; S00 += v11.x*H0_11;
            S00 += v15.x*H0_15; S00 += v16.x*H0_16; S00 += v17.x*H0_17;
            S00 += v18.x*H0_18; S00 += v19.x*H0_19; S00 += v20.x*H0_20;
            S01 += v3.x*H1_3;  S01 += v4.x*H1_4;  S01 += v5.x*H1_5;
            S01 += v9.x*H1_9;  S01 += v10.x*H1_10; S01 += v11.x*H1_11;
            S01 += v15.x*H1_15; S01 += v16.x*H1_16; S01 += v17.x*H1_17;
            S01 += v18.x*H1_18; S01 += v19.x*H1_19; S01 += v20.x*H1_20;
            S10 += v3.y*H0_3;  S10 += v4.y*H0_4;  S10 += v5.y*H0_5;
            S10 += v9.y*H0_9;  S10 += v10.y*H0_10; S10 += v11.y*H0_11;
            S10 += v15.y*H0_15; S10 += v16.y*H0_16; S10 += v17.y*H0_17;
            S10 += v18.y*H0_18; S10 += v19.y*H0_19; S10 += v20.y*H0_20;
            S11 += v3.y*H1_3;  S11 += v4.y*H1_4;  S11 += v5.y*H1_5;
            S11 += v9.y*H1_9;  S11 += v10.y*H1_10; S11 += v11.y*H1_11;
            S11 += v15.y*H1_15; S11 += v16.y*H1_16; S11 += v17.y*H1_17;
            S11 += v18.y*H1_18; S11 += v19.y*H1_19; S11 += v20.y*H1_20;
            S00 += mcv0; S11 += mcv1;
            if (l < 21) {
                const float4 own = *(const float4*)&sHpack[l*4];
                const float b0 = own.z, b1 = own.w;
                float x0, x1;
                if (fabsf(S00) >= fabsf(S10)) {        // LU partial pivot (ties keep row 0)
                    const float fac = S10/S00;
                    x1 = (b1 - fac*b0) / (S11 - fac*S01);
                    x0 = (b0 - S01*x1) / S00;
                } else {
                    const float fac = S00/S10;
                    x1 = (b0 - fac*b1) / (S01 - fac*S11);
                    x0 = (b1 - S11*x1) / S10;
                }
                float4 kp; kp.x = x0; kp.y = x1;
                kp.z = S00*x0 + S01*x1;
                kp.w = S10*x0 + S11*x1;
                *(float4*)&sKpack[l*4] = kp;
                sdx[l] = x0*r0s + x1*r1s;
            }
        }
        WSYNC();                        // (6) sKpack/sdx visible

        // ================= Joseph update + state update =================
#pragma unroll
        for (int q = 0; q < 7; ++q) {
            const float4 Ki = *(const float4*)&sKpack[ei[q]*4];
            const float4 Kj = *(const float4*)&sKpack[ej[q]*4];
            const float4 Hi = *(const float4*)&sHpack[ei[q]*4];
            const float4 Hj = *(const float4*)&sHpack[ej[q]*4];
            const float pn_ji = sPnT[ei[q]*P24 + ej[q]];
            const float puij = Pnreg[q] - (Ki.x*Hj.x + Ki.y*Hj.y) - (Hi.z*Kj.x + Hi.w*Kj.y)
                                        + (Ki.x*Kj.z + Ki.y*Kj.w);
            const float puji = pn_ji   - (Kj.x*Hi.x + Kj.y*Hi.y) - (Hj.z*Ki.x + Hj.w*Ki.y)
                                        + (Kj.x*Ki.z + Kj.y*Ki.w);
            const float pu = 0.5f*(puij + puji);
            Preg[q] = ev[q] ? pu : Preg[q];
        }
        {
            float dxr[21];
#pragma unroll
            for (int q2=0;q2<6;q2++){
                const float4 x = *(const float4*)(&sdx[4*q2]);
                dxr[4*q2] = x.x;
                if (4*q2+1 < 21) dxr[4*q2+1] = x.y;
                if (4*q2+2 < 21) dxr[4*q2+2] = x.z;
                if (4*q2+3 < 21) dxr[4*q2+3] = x.w;
            }
            float dR[9], Jm[9];
            const float q0 = dxr[0], q1 = dxr[1], q2 = dxr[2];
            const float sq = q0*q0 + q1*q1 + q2*q2;
            if (sq < 1e-16f) {
                dR[0]=1.f; dR[1]=-q2; dR[2]=q1;
                dR[3]=q2;  dR[4]=1.f; dR[5]=-q0;
                dR[6]=-q1; dR[7]=q0;  dR[8]=1.f;
                Jm[0]=1.f;      Jm[1]=-0.5f*q2; Jm[2]=0.5f*q1;
                Jm[3]=0.5f*q2;  Jm[4]=1.f;      Jm[5]=-0.5f*q0;
                Jm[6]=-0.5f*q1; Jm[7]=0.5f*q0;  Jm[8]=1.f;
            } else {
                const float ang = sqrtf(sq);
                const float ax=q0/ang, ay=q1/ang, az=q2/ang;
                const float s=sinf(ang), c=cosf(ang), o=1.f-c;
                dR[0]=c+o*ax*ax;    dR[1]=o*ax*ay-s*az; dR[2]=o*ax*az+s*ay;
                dR[3]=o*ay*ax+s*az; dR[4]=c+o*ay*ay;    dR[5]=o*ay*az-s*ax;
                dR[6]=o*az*ax-s*ay; dR[7]=o*az*ay+s*ax; dR[8]=c+o*az*az;
                const float sa  = s/ang;
                const float osa = 1.f - sa;
                const float tt  = o/ang;
                Jm[0]=sa+osa*ax*ax;    Jm[1]=osa*ax*ay-tt*az; Jm[2]=osa*ax*az+tt*ay;
                Jm[3]=osa*ay*ax+tt*az; Jm[4]=sa+osa*ay*ay;    Jm[5]=osa*ay*az-tt*ax;
                Jm[6]=osa*az*ax-tt*ay; Jm[7]=osa*az*ay+tt*ax; Jm[8]=sa+osa*az*az;
            }
            float nR[9]; m3mul_dev(dR, Rot_n, nR);
#pragma unroll
            for (int c=0;c<9;c++) Rot[c] = nR[c];
            const float dv0 = Jm[0]*dxr[3] + Jm[1]*dxr[4] + Jm[2]*dxr[5];
            const float dv1 = Jm[3]*dxr[3] + Jm[4]*dxr[4] + Jm[5]*dxr[5];
            const float dv2 = Jm[6]*dxr[3] + Jm[7]*dxr[4] + Jm[8]*dxr[5];
            const float dp0 = Jm[0]*dxr[6] + Jm[1]*dxr[7] + Jm[2]*dxr[8];
            const float dp1 = Jm[3]*dxr[6] + Jm[4]*dxr[7] + Jm[5]*dxr[8];
            const float dp2 = Jm[6]*dxr[6] + Jm[7]*dxr[7] + Jm[8]*dxr[8];
            const float nv0 = dR[0]*v_n[0] + dR[1]*v_n[1] + dR[2]*v_n[2] + dv0;
            const float nv1 = dR[3]*v_n[0] + dR[4]*v_n[1] + dR[5]*v_n[2] + dv1;
            const float nv2 = dR[6]*v_n[0] + dR[7]*v_n[1] + dR[8]*v_n[2] + dv2;
            const float np0 = dR[0]*p_n[0] + dR[1]*p_n[1] + dR[2]*p_n[2] + dp0;
            const float np1 = dR[3]*p_n[0] + dR[4]*p_n[1] + dR[5]*p_n[2] + dp1;
            const float np2v= dR[6]*p_n[0] + dR[7]*p_n[1] + dR[8]*p_n[2] + dp2;
            vv[0]=nv0; vv[1]=nv1; vv[2]=nv2;
            pp[0]=np0; pp[1]=np1; pp[2]=np2v;
            bw[0]+=dxr[9];  bw[1]+=dxr[10]; bw[2]+=dxr[11];
            ba[0]+=dxr[12]; ba[1]+=dxr[13]; ba[2]+=dxr[14];
            float E2[9]; so3exp_dev(dxr[15], dxr[16], dxr[17], E2);
            float nRc[9]; m3mul_dev(E2, Rci, nRc);
#pragma unroll
            for (int c=0;c<9;c++) Rci[c] = nRc[c];
            tci[0]+=dxr[18]; tci[1]+=dxr[19]; tci[2]+=dxr[20];
        }
        STORE_TRAJ(n+1);

        // ---- rotate software pipeline ----
        t_cur = tn_c;
        tn_c  = tn_n;
        uc0=un0; uc1=un1; uc2=un2; uc3=un3; uc4=un4; uc5=un5;
        mcc0=mcn0; mcc1=mcn1;
        // WAR safety: next stage-A writes (sRows/sPhiC) have last readers >=2
        // WSYNCs upstream in this iteration; sAT/sT1/sPn/sPnT/sHpack/sKpack/sdx
        // likewise. Single-wave in-order DS pipe + WSYNCs give RAW ordering.
    }
}

extern "C" void kernel_launch(void* const* d_in, const int* in_sizes, int n_in,
                              void* d_out, int out_size, void* d_ws, size_t ws_size,
                              hipStream_t stream) {
    const float* t     = (const float*)d_in[0];
    const float* u     = (const float*)d_in[1];
    const float* mc    = (const float*)d_in[2];
    const float* v_mes = (const float*)d_in[3];
    const float* ang0  = (const float*)d_in[5];
    float* out = (float*)d_out;
    const int N = in_sizes[0];
    (void)d_ws; (void)ws_size; (void)n_in; (void)out_size;
    iekf_scan_kernel<<<1, 64, 0, stream>>>(t, u, mc, v_mes, ang0, out, N);
}

// Round 8
// 166521.741 us; speedup vs baseline: 1.6899x; 1.2153x over previous
//
#include <hip/hip_runtime.h>
#include <math.h>

// Invariant-EKF sequential scan, SINGLE WAVE, column-ownership edition.
// Round-7 post-mortem: 28.7M LDS bank-conflict cycles (pitch-24 rows -> 4
// bank-groups, 16-way conflicts on every b128 row read + scatter write).
// Fix: P is symmetric -> lane j owns COLUMN j of P in registers. A and
// T1=Phi@A are register-only (uniform Phi coeffs in all lanes); only two
// 21x21 transposes go through LDS (21 conflict-free scalar writes + 6
// pitch-36 b128 row reads each, 3-way max). Pn=T1@Phi^T register-only
// (row ownership). HP/HPT/S/solve/Joseph use broadcast reads + own regs.
// 4 lgkmcnt syncs/step. Expression shapes/order match the passing kernel.

#define GRAV 9.80665f
#define PIT 36   // LDS row pitch (floats) = 144B: 16B-aligned, gcd(36,32)=4
#define Q0c 0.001f
#define Q1c 0.01f

#define WSYNC() asm volatile("s_waitcnt lgkmcnt(0)" ::: "memory")

__device__ __forceinline__ float sel3f(int r, float a, float b, float c) {
    return (r == 0) ? a : ((r == 1) ? b : c);
}

__device__ __forceinline__ void m3mul_dev(const float* A, const float* B, float* C) {
#pragma unroll
    for (int i = 0; i < 3; ++i) {
#pragma unroll
        for (int j = 0; j < 3; ++j) {
            C[i*3+j] = A[i*3+0]*B[j] + A[i*3+1]*B[3+j] + A[i*3+2]*B[6+j];
        }
    }
}

__device__ __forceinline__ void so3exp_dev(float p0, float p1, float p2, float* R) {
    float sq = p0*p0 + p1*p1 + p2*p2;
    if (sq < 1e-16f) {
        R[0]=1.f;  R[1]=-p2;  R[2]=p1;
        R[3]=p2;   R[4]=1.f;  R[5]=-p0;
        R[6]=-p1;  R[7]=p0;   R[8]=1.f;
    } else {
        float ang = sqrtf(sq);
        float ax=p0/ang, ay=p1/ang, az=p2/ang;
        float s=sinf(ang), c=cosf(ang), o=1.f-c;
        R[0]=c+o*ax*ax;    R[1]=o*ax*ay-s*az; R[2]=o*ax*az+s*ay;
        R[3]=o*ay*ax+s*az; R[4]=c+o*ay*ay;    R[5]=o*ay*az-s*ax;
        R[6]=o*az*ax-s*ay; R[7]=o*az*ay+s*ax; R[8]=c+o*az*az;
    }
}

// lanes 0..32 write the 33 trajectory scalars for row NIDX
#define STORE_TRAJ(NIDX)                                                        \
    do {                                                                        \
        if (l < 33) {                                                           \
            float val = Rot[0];                                                 \
            if (l==1) val=Rot[1];  if (l==2) val=Rot[2];                        \
            if (l==3) val=Rot[3];  if (l==4) val=Rot[4];                        \
            if (l==5) val=Rot[5];  if (l==6) val=Rot[6];                        \
            if (l==7) val=Rot[7];  if (l==8) val=Rot[8];                        \
            if (l==9)  val=vv[0];  if (l==10) val=vv[1];  if (l==11) val=vv[2]; \
            if (l==12) val=pp[0];  if (l==13) val=pp[1];  if (l==14) val=pp[2]; \
            if (l==15) val=bw[0];  if (l==16) val=bw[1];  if (l==17) val=bw[2]; \
            if (l==18) val=ba[0];  if (l==19) val=ba[1];  if (l==20) val=ba[2]; \
            if (l==21) val=Rci[0]; if (l==22) val=Rci[1]; if (l==23) val=Rci[2];\
            if (l==24) val=Rci[3]; if (l==25) val=Rci[4]; if (l==26) val=Rci[5];\
            if (l==27) val=Rci[6]; if (l==28) val=Rci[7]; if (l==29) val=Rci[8];\
            if (l==30) val=tci[0]; if (l==31) val=tci[1]; if (l==32) val=tci[2];\
            out[ob + os_ * (NIDX) + orr] = val;                                 \
        }                                                                       \
    } while (0)

__global__ __launch_bounds__(64, 1)
void iekf_scan_kernel(const float* __restrict__ t,
                      const float* __restrict__ u,
                      const float* __restrict__ mc,
                      const float* __restrict__ v_mes,
                      const float* __restrict__ ang0,
                      float* __restrict__ out,
                      const int N)
{
    __shared__ __align__(16) float sT1[21*PIT];   // T1 row-major (transpose #1)
    __shared__ __align__(16) float sPT[21*PIT];   // Pn^T row-major (transpose #2)
    __shared__ __align__(16) float sHK[21*4];     // (hp0,hp1,ht0,ht1) per column
    __shared__ __align__(16) float sKK[21*4];     // (k0,k1,ks0,ks1) per column
    __shared__ __align__(16) float sdx[24];

    const int l = (int)threadIdx.x;
    const int jc = (l < 21) ? l : 20;   // owned column (clamped for idle lanes)
    const bool own = (l < 21);

    if (l >= 21 && l < 24) sdx[l] = 0.f;   // pad for float4 broadcast reads

    // ---- small state (replicated in all lanes) ----
    float Rot[9], vv[3], pp[3], bw[3], ba[3], Rci[9], tci[3];
    {
        const float roll = ang0[0], pitch = ang0[1], yaw = ang0[2];
        const float cr = cosf(roll),  srl = sinf(roll);
        const float cp = cosf(pitch), spt = sinf(pitch);
        const float cy = cosf(yaw),   syw = sinf(yaw);
        float rx[9] = {1.f,0.f,0.f, 0.f,cr,-srl, 0.f,srl,cr};
        float ry[9] = {cp,0.f,spt, 0.f,1.f,0.f, -spt,0.f,cp};
        float rz[9] = {cy,-syw,0.f, syw,cy,0.f, 0.f,0.f,1.f};
        float tm[9]; m3mul_dev(rz, ry, tm);
        m3mul_dev(tm, rx, Rot);
        vv[0]=v_mes[0]; vv[1]=v_mes[1]; vv[2]=v_mes[2];
#pragma unroll
        for (int c=0;c<3;c++){ pp[c]=0.f; bw[c]=0.f; ba[c]=0.f; tci[c]=0.f; }
        Rci[0]=1.f;Rci[1]=0.f;Rci[2]=0.f;Rci[3]=0.f;Rci[4]=1.f;Rci[5]=0.f;
        Rci[6]=0.f;Rci[7]=0.f;Rci[8]=1.f;
    }

    // ---- P column j in registers (P symmetric -> col == row) ----
    float Pcol[21];
#pragma unroll
    for (int i=0;i<21;i++){
        float pd = 0.f;
        if (i==0 || i==1)        pd = 0.001f;
        else if (i==3 || i==4)   pd = 0.1f;
        else if (i>=9  && i<12)  pd = 0.006f;
        else if (i>=12 && i<15)  pd = 0.004f;
        else if (i>=15 && i<18)  pd = 1e-6f;
        else if (i>=18)          pd = 0.005f;
        Pcol[i] = (own && i==jc) ? pd : 0.f;
    }

    // ---- output address constants ----
    int ob=0, os_=0, orr=0;
    if (l<33) {
        if (l<9)       { ob = 0;    os_ = 9; orr = l;    }
        else if (l<12) { ob = 9*N;  os_ = 3; orr = l-9;  }
        else if (l<15) { ob = 12*N; os_ = 3; orr = l-12; }
        else if (l<18) { ob = 15*N; os_ = 3; orr = l-15; }
        else if (l<21) { ob = 18*N; os_ = 3; orr = l-18; }
        else if (l<30) { ob = 21*N; os_ = 9; orr = l-21; }
        else           { ob = 30*N; os_ = 3; orr = l-30; }
    }

    STORE_TRAJ(0);

    float t_cur = t[0];

    // ---- software-pipelined inputs ----
    float tn_c = t[1];
    float uc0,uc1,uc2,uc3,uc4,uc5;
    { const float* un = u + 6; uc0=un[0]; uc1=un[1]; uc2=un[2]; uc3=un[3]; uc4=un[4]; uc5=un[5]; }
    float mcc0 = mc[2], mcc1 = mc[3];

    for (int n = 0; n < N-1; ++n) {
        const int np2 = (n+2 < N) ? (n+2) : (N-1);
        const float tn_n = t[np2];
        float un0,un1,un2,un3,un4,un5;
        { const float* un = u + (size_t)np2*6; un0=un[0]; un1=un[1]; un2=un[2]; un3=un[3]; un4=un[4]; un5=un[5]; }
        const float mcn0 = mc[2*np2], mcn1 = mc[2*np2+1];

        const float dt  = tn_c - t_cur;
        const float dt2 = dt*dt;
        const float u0=uc0,u1=uc1,u2=uc2,u3=uc3,u4=uc4,u5=uc5;
        const float mcv0=mcc0, mcv1=mcc1;

        // ========== stage A: state prop + M1/M2 + in-register H (all lanes) ==========
        float Rot_n[9], v_n[3], p_n[3], om[3], M1[9], M2[9];
        om[0]=u0-bw[0]; om[1]=u1-bw[1]; om[2]=u2-bw[2];
        {
            const float ai0=u3-ba[0], ai1=u4-ba[1], ai2=u5-ba[2];
            const float ac0 = Rot[0]*ai0 + Rot[1]*ai1 + Rot[2]*ai2;
            const float ac1 = Rot[3]*ai0 + Rot[4]*ai1 + Rot[5]*ai2;
            const float ac2 = Rot[6]*ai0 + Rot[7]*ai1 + Rot[8]*ai2 - GRAV;
            v_n[0]=vv[0]+ac0*dt; v_n[1]=vv[1]+ac1*dt; v_n[2]=vv[2]+ac2*dt;
            p_n[0]=pp[0]+vv[0]*dt+0.5f*ac0*dt2;
            p_n[1]=pp[1]+vv[1]*dt+0.5f*ac1*dt2;
            p_n[2]=pp[2]+vv[2]*dt+0.5f*ac2*dt2;
            float E[9]; so3exp_dev(om[0]*dt, om[1]*dt, om[2]*dt, E);
            m3mul_dev(Rot, E, Rot_n);
        }
#pragma unroll
        for (int c=0;c<3;c++) {
            M1[0+c] = -vv[2]*Rot[3+c] + vv[1]*Rot[6+c];
            M1[3+c] =  vv[2]*Rot[0+c] - vv[0]*Rot[6+c];
            M1[6+c] = -vv[1]*Rot[0+c] + vv[0]*Rot[3+c];
            M2[0+c] = -pp[2]*Rot[3+c] + pp[1]*Rot[6+c];
            M2[3+c] =  pp[2]*Rot[0+c] - pp[0]*Rot[6+c];
            M2[6+c] = -pp[1]*Rot[0+c] + pp[0]*Rot[3+c];
        }
        const float hdt2 = 0.5f*dt2;
        const float sdt3 = dt*dt2*(1.0f/6.0f);
        const float dtg = dt*GRAV, hg = hdt2*GRAV;

        // in-register H coefficients (uniform across lanes) + residual
        float H0_3,H0_4,H0_5,H1_3,H1_4,H1_5,H0_9,H0_10,H0_11,H1_9,H1_10,H1_11;
        float H0_15,H0_16,H0_17,H1_15,H1_16,H1_17,H0_18,H0_19,H0_20,H1_18,H1_19,H1_20;
        float r0s, r1s;
        {
            float Rb[9]; m3mul_dev(Rot_n, Rci, Rb);
            const float vi0 = Rot_n[0]*v_n[0] + Rot_n[3]*v_n[1] + Rot_n[6]*v_n[2];
            const float vi1 = Rot_n[1]*v_n[0] + Rot_n[4]*v_n[1] + Rot_n[7]*v_n[2];
            const float vi2 = Rot_n[2]*v_n[0] + Rot_n[5]*v_n[1] + Rot_n[8]*v_n[2];
            H0_3 = Rb[1]; H0_4 = Rb[4]; H0_5 = Rb[7];
            H1_3 = Rb[2]; H1_4 = Rb[5]; H1_5 = Rb[8];
            H0_9 = tci[2]; H0_10 = 0.f; H0_11 = -tci[0];
            H1_9 = -tci[1]; H1_10 = tci[0]; H1_11 = 0.f;
            H0_15 =  Rci[4]*vi2 - Rci[7]*vi1;
            H0_16 = -Rci[1]*vi2 + Rci[7]*vi0;
            H0_17 =  Rci[1]*vi1 - Rci[4]*vi0;
            H1_15 =  Rci[5]*vi2 - Rci[8]*vi1;
            H1_16 = -Rci[2]*vi2 + Rci[8]*vi0;
            H1_17 =  Rci[2]*vi1 - Rci[5]*vi0;
            H0_18 = -om[2]; H0_19 = 0.f; H0_20 = om[0];
            H1_18 = om[1];  H1_19 = -om[0]; H1_20 = 0.f;
            const float vb1 = Rci[1]*vi0 + Rci[4]*vi1 + Rci[7]*vi2 + (tci[2]*om[0] - tci[0]*om[2]);
            const float vb2 = Rci[2]*vi0 + Rci[5]*vi1 + Rci[8]*vi2 + (tci[0]*om[1] - tci[1]*om[0]);
            r0s = -vb1; r1s = -vb2;
        }

        // ========== A = P + G Q G^T  (column j, registers only) ==========
        // row j of Rot/M1/M2 (runtime-j select; garbage for j>=9, gated)
        const int jb = jc/3, rj = jc - 3*jb;
        float mj0,mj1,mj2;
        {
            const float t0 = sel3f(rj,Rot[0],Rot[3],Rot[6]);
            const float t1 = sel3f(rj,Rot[1],Rot[4],Rot[7]);
            const float t2 = sel3f(rj,Rot[2],Rot[5],Rot[8]);
            const float a0 = sel3f(rj,M1[0],M1[3],M1[6]);
            const float a1 = sel3f(rj,M1[1],M1[4],M1[7]);
            const float a2 = sel3f(rj,M1[2],M1[5],M1[8]);
            const float b0 = sel3f(rj,M2[0],M2[3],M2[6]);
            const float b1 = sel3f(rj,M2[1],M2[4],M2[7]);
            const float b2 = sel3f(rj,M2[2],M2[5],M2[8]);
            mj0 = sel3f(jb, t0, a0, b0);
            mj1 = sel3f(jb, t1, a1, b1);
            mj2 = sel3f(jb, t2, a2, b2);
        }
        const bool jlt9 = (jc < 9);
        const bool jq1  = (jc >= 3 && jc < 6);
        const int  rq   = jc - 3;
        const float rjq0 = sel3f(rq,Rot[0],Rot[3],Rot[6]);
        const float rjq1 = sel3f(rq,Rot[1],Rot[4],Rot[7]);
        const float rjq2 = sel3f(rq,Rot[2],Rot[5],Rot[8]);

        float Acol[21];
#pragma unroll
        for (int i=0;i<21;i++){
            float W;
            if (i < 9) {
                const float mi0 = (i<3)?Rot[i*3+0] : (i<6)?M1[(i-3)*3+0] : M2[(i-6)*3+0];
                const float mi1 = (i<3)?Rot[i*3+1] : (i<6)?M1[(i-3)*3+1] : M2[(i-6)*3+1];
                const float mi2 = (i<3)?Rot[i*3+2] : (i<6)?M1[(i-3)*3+2] : M2[(i-6)*3+2];
                float w = dt2*Q0c*(mi0*mj0 + mi1*mj1 + mi2*mj2);
                if (i>=3 && i<6) {
                    const float ri0 = Rot[(i-3)*3+0], ri1 = Rot[(i-3)*3+1], ri2 = Rot[(i-3)*3+2];
                    const float w2 = w + dt2*Q1c*(ri0*rjq0 + ri1*rjq1 + ri2*rjq2);
                    w = jq1 ? w2 : w;
                }
                W = jlt9 ? w : 0.f;
            } else {
                const float qd = (i<12)?6e-9f : (i<15)?2e-4f : 1e-9f;
                W = (own && i==jc) ? dt2*qd : 0.f;
            }
            Acol[i] = Pcol[i] + W;
        }

        // ========== Phi row coefficients (uniform, all lanes) ==========
        float cbw[9][3], cba[9][3];
#pragma unroll
        for (int i=0;i<9;i++){
            const int br=i/3, r=i-3*br;
#pragma unroll
            for (int c=0;c<3;c++){
                const float m0r = (r==0)?Rot[c]:(r==1)?Rot[3+c]:Rot[6+c];
                const float m1r = (r==0)?M1[c]:(r==1)?M1[3+c]:M1[6+c];
                const float m2r = (r==0)?M2[c]:(r==1)?M2[3+c]:M2[6+c];
                const float sgm = (r==0)? GRAV*Rot[3+c] : (r==1)? -GRAV*Rot[0+c] : 0.f;
                cbw[i][c] = (br==0)? (-dt*m0r) : (br==1)? (-dt*m1r - hdt2*sgm)
                                               : (-dt*m2r - hdt2*m1r - sdt3*sgm);
                cba[i][c] = (br==0)? 0.f : (br==1)? (-dt*m0r) : (-hdt2*m0r);
            }
        }

        // ========== T1 = Phi @ A  (column j, registers only) ==========
        float T1col[21];
#pragma unroll
        for (int i=0;i<21;i++){
            if (i < 9) {
                const int br=i/3, r=i-3*br;
                const float ca0 = (br==1)? ((r==1)? -dtg:0.f) : (br==2)? ((r==1)? -hg:0.f) : 0.f;
                const float ca1 = (br==1)? ((r==0)?  dtg:0.f) : (br==2)? ((r==0)?  hg:0.f) : 0.f;
                const float cv0 = (br==2 && r==0)? dt : 0.f;
                const float cv1 = (br==2 && r==1)? dt : 0.f;
                const float cv2 = (br==2 && r==2)? dt : 0.f;
                float tv = Acol[i];
                tv += ca0*Acol[0];
                tv += ca1*Acol[1];
                tv += cv0*Acol[3];
                tv += cv1*Acol[4];
                tv += cv2*Acol[5];
                tv += cbw[i][0]*Acol[9];
                tv += cbw[i][1]*Acol[10];
                tv += cbw[i][2]*Acol[11];
                tv += cba[i][0]*Acol[12];
                tv += cba[i][1]*Acol[13];
                tv += cba[i][2]*Acol[14];
                T1col[i] = tv;
            } else {
                T1col[i] = Acol[i];
            }
        }

        // ========== transpose #1: T1 columns -> rows ==========
        if (own) {
#pragma unroll
            for (int i=0;i<21;i++) sT1[i*PIT + l] = T1col[i];   // conflict-free
        }
        WSYNC();
        float T1row[21];
        {
            const float* rp = &sT1[jc*PIT];
            const float4 a0 = *(const float4*)(rp+0);
            const float4 a1 = *(const float4*)(rp+4);
            const float4 a2 = *(const float4*)(rp+8);
            const float4 a3 = *(const float4*)(rp+12);
            const float4 a4 = *(const float4*)(rp+16);
            const float4 a5 = *(const float4*)(rp+20);
            T1row[0]=a0.x;  T1row[1]=a0.y;  T1row[2]=a0.z;  T1row[3]=a0.w;
            T1row[4]=a1.x;  T1row[5]=a1.y;  T1row[6]=a1.z;  T1row[7]=a1.w;
            T1row[8]=a2.x;  T1row[9]=a2.y;  T1row[10]=a2.z; T1row[11]=a2.w;
            T1row[12]=a3.x; T1row[13]=a3.y; T1row[14]=a3.z; T1row[15]=a3.w;
            T1row[16]=a4.x; T1row[17]=a4.y; T1row[18]=a4.z; T1row[19]=a4.w;
            T1row[20]=a5.x;
        }

        // ========== Pn = T1 @ Phi^T  (row j, registers only) ==========
        float Pnrow[21];
#pragma unroll
        for (int m=0;m<21;m++){
            if (m < 9) {
                const int br=m/3, r=m-3*br;
                const float ca0 = (br==1)? ((r==1)? -dtg:0.f) : (br==2)? ((r==1)? -hg:0.f) : 0.f;
                const float ca1 = (br==1)? ((r==0)?  dtg:0.f) : (br==2)? ((r==0)?  hg:0.f) : 0.f;
                const float cv0 = (br==2 && r==0)? dt : 0.f;
                const float cv1 = (br==2 && r==1)? dt : 0.f;
                const float cv2 = (br==2 && r==2)? dt : 0.f;
                float pv = T1row[m];
                pv += ca0*T1row[0];
                pv += ca1*T1row[1];
                pv += cv0*T1row[3];
                pv += cv1*T1row[4];
                pv += cv2*T1row[5];
                pv += cbw[m][0]*T1row[9];
                pv += cbw[m][1]*T1row[10];
                pv += cbw[m][2]*T1row[11];
                pv += cba[m][0]*T1row[12];
                pv += cba[m][1]*T1row[13];
                pv += cba[m][2]*T1row[14];
                Pnrow[m] = pv;
            } else {
                Pnrow[m] = T1row[m];
            }
        }

        // ========== transpose #2: Pn rows -> columns ==========
        if (own) {
#pragma unroll
            for (int m=0;m<21;m++) sPT[m*PIT + l] = Pnrow[m];   // conflict-free
        }
        WSYNC();
        float Pncol[21];
        {
            const float* rp = &sPT[jc*PIT];
            const float4 a0 = *(const float4*)(rp+0);
            const float4 a1 = *(const float4*)(rp+4);
            const float4 a2 = *(const float4*)(rp+8);
            const float4 a3 = *(const float4*)(rp+12);
            const float4 a4 = *(const float4*)(rp+16);
            const float4 a5 = *(const float4*)(rp+20);
            Pncol[0]=a0.x;  Pncol[1]=a0.y;  Pncol[2]=a0.z;  Pncol[3]=a0.w;
            Pncol[4]=a1.x;  Pncol[5]=a1.y;  Pncol[6]=a1.z;  Pncol[7]=a1.w;
            Pncol[8]=a2.x;  Pncol[9]=a2.y;  Pncol[10]=a2.z; Pncol[11]=a2.w;
            Pncol[12]=a3.x; Pncol[13]=a3.y; Pncol[14]=a3.z; Pncol[15]=a3.w;
            Pncol[16]=a4.x; Pncol[17]=a4.y; Pncol[18]=a4.z; Pncol[19]=a4.w;
            Pncol[20]=a5.x;
        }

        // ========== HP/HPT column j (registers) ==========
        float hp0=0.f, hp1=0.f, ht0=0.f, ht1=0.f;
        hp0 += H0_3*Pncol[3];   hp0 += H0_4*Pncol[4];   hp0 += H0_5*Pncol[5];
        hp0 += H0_9*Pncol[9];   hp0 += H0_10*Pncol[10]; hp0 += H0_11*Pncol[11];
        hp0 += H0_15*Pncol[15]; hp0 += H0_16*Pncol[16]; hp0 += H0_17*Pncol[17];
        hp0 += H0_18*Pncol[18]; hp0 += H0_19*Pncol[19]; hp0 += H0_20*Pncol[20];
        hp1 += H1_3*Pncol[3];   hp1 += H1_4*Pncol[4];   hp1 += H1_5*Pncol[5];
        hp1 += H1_9*Pncol[9];   hp1 += H1_10*Pncol[10]; hp1 += H1_11*Pncol[11];
        hp1 += H1_15*Pncol[15]; hp1 += H1_16*Pncol[16]; hp1 += H1_17*Pncol[17];
        hp1 += H1_18*Pncol[18]; hp1 += H1_19*Pncol[19]; hp1 += H1_20*Pncol[20];
        ht0 += H0_3*Pnrow[3];   ht0 += H0_4*Pnrow[4];   ht0 += H0_5*Pnrow[5];
        ht0 += H0_9*Pnrow[9];   ht0 += H0_10*Pnrow[10]; ht0 += H0_11*Pnrow[11];
        ht0 += H0_15*Pnrow[15]; ht0 += H0_16*Pnrow[16]; ht0 += H0_17*Pnrow[17];
        ht0 += H0_18*Pnrow[18]; ht0 += H0_19*Pnrow[19]; ht0 += H0_20*Pnrow[20];
        ht1 += H1_3*Pnrow[3];   ht1 += H1_4*Pnrow[4];   ht1 += H1_5*Pnrow[5];
        ht1 += H1_9*Pnrow[9];   ht1 += H1_10*Pnrow[10]; ht1 += H1_11*Pnrow[11];
        ht1 += H1_15*Pnrow[15]; ht1 += H1_16*Pnrow[16]; ht1 += H1_17*Pnrow[17];
        ht1 += H1_18*Pnrow[18]; ht1 += H1_19*Pnrow[19]; ht1 += H1_20*Pnrow[20];
        if (own) {
            float4 hk; hk.x=hp0; hk.y=hp1; hk.z=ht0; hk.w=ht1;
            *(float4*)&sHK[l*4] = hk;
        }
        WSYNC();

        // ========== S (all lanes, broadcast reads) + solve + K (own col) ==========
        float x0, x1, ks0, ks1;
        {
            const float4 v3  = *(const float4*)&sHK[3*4];
            const float4 v4  = *(const float4*)&sHK[4*4];
            const float4 v5  = *(const float4*)&sHK[5*4];
            const float4 v9  = *(const float4*)&sHK[9*4];
            const float4 v10 = *(const float4*)&sHK[10*4];
            const float4 v11 = *(const float4*)&sHK[11*4];
            const float4 v15 = *(const float4*)&sHK[15*4];
            const float4 v16 = *(const float4*)&sHK[16*4];
            const float4 v17 = *(const float4*)&sHK[17*4];
            const float4 v18 = *(const float4*)&sHK[18*4];
            const float4 v19 = *(const float4*)&sHK[19*4];
            const float4 v20 = *(const float4*)&sHK[20*4];
            float S00 = 0.f, S01 = 0.f, S10 = 0.f, S11 = 0.f;
            S00 += v3.x*H0_3;  S00 += v4.x*H0_4;  S00 += v5.x*H0_5;
            S00 += v9.x*H0_9;  S00 += v10.x*H0_10; S00 += v11.x*H0_11;
            S00 += v15.x*H0_15; S00 += v16.x*H0_16; S00 += v17.x*H0_17;
            S00 += v18.x*H0_18; S00 += v19.x*H0_19; S00 += v20.x*H0_20;
            S01 += v3.x*H1_3;  S01 += v4.x*H1_4;  S01 += v5.x*H1_5;
            S01 += v9.x*H1_9;  S01 += v10.x*H1_10; S01 += v11.x*H1_11;
            S01 += v15.x*H1_15; S01 += v16.x*H1_16; S01 += v17.x*H1_17;
            S01 += v18.x*H1_18; S01 += v19.x*H1_19; S01 += v20.x*H1_20;
            S10 += v3.y*H0_3;  S10 += v4.y*H0_4;  S10 += v5.y*H0_5;
            S10 += v9.y*H0_9;  S10 += v10.y*H0_10; S10 += v11.y*H0_11;
            S10 += v15.y*H0_15; S10 += v16.y*H0_16; S10 += v17.y*H0_17;
            S10 += v18.y*H0_18; S10 += v19.y*H0_19; S10 += v20.y*H0_20;
            S11 += v3.y*H1_3;  S11 += v4.y*H1_4;  S11 += v5.y*H1_5;
            S11 += v9.y*H1_9;  S11 += v10.y*H1_10; S11 += v11.y*H1_11;
            S11 += v15.y*H1_15; S11 += v16.y*H1_16; S11 += v17.y*H1_17;
            S11 += v18.y*H1_18; S11 += v19.y*H1_19; S11 += v20.y*H1_20;
            S00 += mcv0; S11 += mcv1;
            const float b0 = ht0, b1 = ht1;
            if (fabsf(S00) >= fabsf(S10)) {        // LU partial pivot (ties keep row 0)
                const float fac = S10/S00;
                x1 = (b1 - fac*b0) / (S11 - fac*S01);
                x0 = (b0 - S01*x1) / S00;
            } else {
                const float fac = S00/S10;
                x1 = (b0 - fac*b1) / (S01 - fac*S11);
                x0 = (b1 - S11*x1) / S10;
            }
            ks0 = S00*x0 + S01*x1;
            ks1 = S10*x0 + S11*x1;
            if (own) {
                float4 kp; kp.x=x0; kp.y=x1; kp.z=ks0; kp.w=ks1;
                *(float4*)&sKK[l*4] = kp;
                sdx[l] = x0*r0s + x1*r1s;
            }
        }
        WSYNC();

        // ========== Joseph update (both orientations, new P column j) ==========
#pragma unroll
        for (int i=0;i<21;i++){
            const float4 Ki = *(const float4*)&sKK[i*4];   // broadcast
            const float4 Hi = *(const float4*)&sHK[i*4];   // broadcast
            const float puij = Pncol[i] - (Ki.x*hp0 + Ki.y*hp1) - (Hi.z*x0 + Hi.w*x1)
                                        + (Ki.x*ks0 + Ki.y*ks1);
            const float puji = Pnrow[i] - (x0*Hi.x + x1*Hi.y) - (ht0*Ki.x + ht1*Ki.y)
                                        + (x0*Ki.z + x1*Ki.w);
            Pcol[i] = 0.5f*(puij + puji);
        }

        // ========== state update (all lanes, uniform) ==========
        {
            float dxr[21];
#pragma unroll
            for (int q2=0;q2<6;q2++){
                const float4 x = *(const float4*)(&sdx[4*q2]);
                dxr[4*q2] = x.x;
                if (4*q2+1 < 21) dxr[4*q2+1] = x.y;
                if (4*q2+2 < 21) dxr[4*q2+2] = x.z;
                if (4*q2+3 < 21) dxr[4*q2+3] = x.w;
            }
            float dR[9], Jm[9];
            const float q0 = dxr[0], q1 = dxr[1], q2 = dxr[2];
            const float sq = q0*q0 + q1*q1 + q2*q2;
            if (sq < 1e-16f) {
                dR[0]=1.f; dR[1]=-q2; dR[2]=q1;
                dR[3]=q2;  dR[4]=1.f; dR[5]=-q0;
                dR[6]=-q1; dR[7]=q0;  dR[8]=1.f;
                Jm[0]=1.f;      Jm[1]=-0.5f*q2; Jm[2]=0.5f*q1;
                Jm[3]=0.5f*q2;  Jm[4]=1.f;      Jm[5]=-0.5f*q0;
                Jm[6]=-0.5f*q1; Jm[7]=0.5f*q0;  Jm[8]=1.f;
            } else {
                const float ang = sqrtf(sq);
                const float ax=q0/ang, ay=q1/ang, az=q2/ang;
                const float s=sinf(ang), c=cosf(ang), o=1.f-c;
                dR[0]=c+o*ax*ax;    dR[1]=o*ax*ay-s*az; dR[2]=o*ax*az+s*ay;
                dR[3]=o*ay*ax+s*az; dR[4]=c+o*ay*ay;    dR[5]=o*ay*az-s*ax;
                dR[6]=o*az*ax-s*ay; dR[7]=o*az*ay+s*ax; dR[8]=c+o*az*az;
                const float sa  = s/ang;
                const float osa = 1.f - sa;
                const float tt  = o/ang;
                Jm[0]=sa+osa*ax*ax;    Jm[1]=osa*ax*ay-tt*az; Jm[2]=osa*ax*az+tt*ay;
                Jm[3]=osa*ay*ax+tt*az; Jm[4]=sa+osa*ay*ay;    Jm[5]=osa*ay*az-tt*ax;
                Jm[6]=osa*az*ax-tt*ay; Jm[7]=osa*az*ay+tt*ax; Jm[8]=sa+osa*az*az;
            }
            float nR[9]; m3mul_dev(dR, Rot_n, nR);
#pragma unroll
            for (int c=0;c<9;c++) Rot[c] = nR[c];
            const float dv0 = Jm[0]*dxr[3] + Jm[1]*dxr[4] + Jm[2]*dxr[5];
            const float dv1 = Jm[3]*dxr[3] + Jm[4]*dxr[4] + Jm[5]*dxr[5];
            const float dv2 = Jm[6]*dxr[3] + Jm[7]*dxr[4] + Jm[8]*dxr[5];
            const float dp0 = Jm[0]*dxr[6] + Jm[1]*dxr[7] + Jm[2]*dxr[8];
            const float dp1 = Jm[3]*dxr[6] + Jm[4]*dxr[7] + Jm[5]*dxr[8];
            const float dp2 = Jm[6]*dxr[6] + Jm[7]*dxr[7] + Jm[8]*dxr[8];
            const float nv0 = dR[0]*v_n[0] + dR[1]*v_n[1] + dR[2]*v_n[2] + dv0;
            const float nv1 = dR[3]*v_n[0] + dR[4]*v_n[1] + dR[5]*v_n[2] + dv1;
            const float nv2 = dR[6]*v_n[0] + dR[7]*v_n[1] + dR[8]*v_n[2] + dv2;
            const float np0 = dR[0]*p_n[0] + dR[1]*p_n[1] + dR[2]*p_n[2] + dp0;
            const float np1 = dR[3]*p_n[0] + dR[4]*p_n[1] + dR[5]*p_n[2] + dp1;
            const float np2v= dR[6]*p_n[0] + dR[7]*p_n[1] + dR[8]*p_n[2] + dp2;
            vv[0]=nv0; vv[1]=nv1; vv[2]=nv2;
            pp[0]=np0; pp[1]=np1; pp[2]=np2v;
            bw[0]+=dxr[9];  bw[1]+=dxr[10]; bw[2]+=dxr[11];
            ba[0]+=dxr[12]; ba[1]+=dxr[13]; ba[2]+=dxr[14];
            float E2[9]; so3exp_dev(dxr[15], dxr[16], dxr[17], E2);
            float nRc[9]; m3mul_dev(E2, Rci, nRc);
#pragma unroll
            for (int c=0;c<9;c++) Rci[c] = nRc[c];
            tci[0]+=dxr[18]; tci[1]+=dxr[19]; tci[2]+=dxr[20];
        }
        STORE_TRAJ(n+1);

        // ---- rotate software pipeline ----
        t_cur = tn_c;
        tn_c  = tn_n;
        uc0=un0; uc1=un1; uc2=un2; uc3=un3; uc4=un4; uc5=un5;
        mcc0=mcn0; mcc1=mcn1;
        // Single wave: DS pipe is in-order per wave, and the WSYNC memory
        // clobbers pin compiler ordering -> no trailing barrier needed.
    }
}

extern "C" void kernel_launch(void* const* d_in, const int* in_sizes, int n_in,
                              void* d_out, int out_size, void* d_ws, size_t ws_size,
                              hipStream_t stream) {
    const float* t     = (const float*)d_in[0];
    const float* u     = (const float*)d_in[1];
    const float* mc    = (const float*)d_in[2];
    const float* v_mes = (const float*)d_in[3];
    const float* ang0  = (const float*)d_in[5];
    float* out = (float*)d_out;
    const int N = in_sizes[0];
    (void)d_ws; (void)ws_size; (void)n_in; (void)out_size;
    iekf_scan_kernel<<<1, 64, 0, stream>>>(t, u, mc, v_mes, ang0, out, N);
}